// Round 3
// baseline (278.275 us; speedup 1.0000x reference)
//
#include <hip/hip_runtime.h>

// ---------------------------------------------------------------------------
// PreferencePredictor: logits[m] over M=131072 candidates.
// Heavy op: l = llm @ Wl^T  (M=131072, K=768, N=256)  -> HBM-bound (403 MB).
// Attention over 2 ctx rows collapses to 4 sigmoid gates + rank-4 update with
// precomputed wsd/csd/base/delta (prep kernel block 96).
// Main loop: 3-buffer global_load_lds ring, prefetch depth 2, counted vmcnt
// (12/6/0) so DMA stays in flight across barriers (T3+T4). A staged fp32 with
// XOR swizzle (row&7)<<4 via inverse-swizzled global src; B staged in MFMA
// fragment order (prep pre-swizzled, linear both sides).
// ws float layout:
//   [0,256) u   [256,512) qv   [512,768) k0  [768,1024) k1
//   [1024,1280) v0  [1280,1536) v1
//   [1536,2560) wsd[4][256]   [2560,2816) base[256]
//   [2816,3840) delta[4][256] [3840,3844) csd[4]
//   float idx 4096: Bs bf16 fragment order Bs[kk(24)][nt(16)][lane(64)][i(8)]
// ---------------------------------------------------------------------------

typedef float f32x4 __attribute__((ext_vector_type(4)));
typedef __bf16 bf16x8 __attribute__((ext_vector_type(8)));

#define VMCNT(n) asm volatile("s_waitcnt vmcnt(" #n ")" ::: "memory")

__device__ __forceinline__ unsigned f2bf(float f) {
  unsigned u = __builtin_bit_cast(unsigned, f);
  u += 0x7fffu + ((u >> 16) & 1u);   // round-to-nearest-even
  return u >> 16;
}

__device__ __forceinline__ void gl_lds16(const void* g, void* l) {
  __builtin_amdgcn_global_load_lds(
      (const __attribute__((address_space(1))) void*)g,
      (__attribute__((address_space(3))) void*)l, 16, 0, 0);
}

// ---- prep: blocks 0..95 = Wl fp32->bf16 fragment swizzle; block 96 = all
// small projections (u,qv,k,v,wsd,csd,base,delta).  (97 x 256) --------------
__global__ void prep_all(const float* __restrict__ user, const float* __restrict__ query,
                         const float* __restrict__ Wu, const float* __restrict__ bu,
                         const float* __restrict__ Wq, const float* __restrict__ bq,
                         const float* __restrict__ Wl,
                         const float* __restrict__ ipw, const float* __restrict__ ipb,
                         const float* __restrict__ opw, const float* __restrict__ opb,
                         float* __restrict__ wf, unsigned int* __restrict__ Bs4) {
  const int t = threadIdx.x;
  if (blockIdx.x < 96) {
    const int tid = blockIdx.x * 256 + t;           // (kk*16+nt)*64+lane
    const int lane = tid & 63;
    const int ntk = tid >> 6;
    const int kk = ntk >> 4, nt = ntk & 15;
    const int k = kk * 32 + (lane >> 4) * 8;
    const int j = nt * 16 + (lane & 15);
    const float* src = Wl + (size_t)j * 768 + k;
    uint4 pk;
    pk.x = f2bf(src[0]) | (f2bf(src[1]) << 16);
    pk.y = f2bf(src[2]) | (f2bf(src[3]) << 16);
    pk.z = f2bf(src[4]) | (f2bf(src[5]) << 16);
    pk.w = f2bf(src[6]) | (f2bf(src[7]) << 16);
    ((uint4*)Bs4)[tid] = pk;
    return;
  }
  // ---- block 96: small chain ----
  __shared__ float sh[1536];  // [0,512) u|qv  [512,1536) k0|k1|v0|v1
  for (int o = t; o < 512; o += 256) {
    const int isq = o >> 8, j = o & 255;
    const float* Wrow = (isq ? Wq : Wu) + (size_t)j * 768;
    const float* vec = isq ? query : user;
    float p = 0.f;
    for (int d = 0; d < 768; ++d) p = fmaf(Wrow[d], vec[d], p);
    p += (isq ? bq[j] : bu[j]);
    sh[o] = p; wf[o] = p;
  }
  __syncthreads();
  for (int o = t; o < 1024; o += 256) {
    const int kv = o >> 9, cc = (o >> 8) & 1, j = o & 255;
    const int row = 256 + kv * 256 + j;             // Wk rows 256..511, Wv 512..767
    const float* Wrow = ipw + (size_t)row * 256;
    const float* ctx = sh + cc * 256;
    float p = 0.f;
    for (int d = 0; d < 256; ++d) p = fmaf(Wrow[d], ctx[d], p);
    p += ipb[row];
    sh[512 + o] = p; wf[512 + o] = p;
  }
  __syncthreads();
  #pragma unroll
  for (int h = 0; h < 4; ++h) {                     // wsd[h][t]
    float acc = 0.f;
    for (int d = 0; d < 64; ++d) {
      const float kd = sh[512 + h * 64 + d] - sh[768 + h * 64 + d];
      acc = fmaf(ipw[(size_t)(h * 64 + d) * 256 + t], kd, acc);
    }
    wf[1536 + h * 256 + t] = 0.125f * acc;
  }
  if (t < 4) {                                      // csd[t]
    float cs = 0.f;
    for (int d = 0; d < 64; ++d)
      cs = fmaf(ipb[t * 64 + d], sh[512 + t * 64 + d] - sh[768 + t * 64 + d], cs);
    wf[3840 + t] = 0.125f * cs;
  }
  const float* oprow = opw + (size_t)t * 256;       // base[t], delta[h][t]
  float bse = 0.f;
  for (int i = 0; i < 256; ++i) bse = fmaf(oprow[i], sh[1280 + i], bse);
  wf[2560 + t] = bse + opb[t];
  #pragma unroll
  for (int h = 0; h < 4; ++h) {
    float dl = 0.f;
    for (int d = 0; d < 64; ++d)
      dl = fmaf(oprow[h * 64 + d], sh[1024 + h * 64 + d] - sh[1280 + h * 64 + d], dl);
    wf[2816 + h * 256 + t] = dl;
  }
}

// ---- main: 64 rows/block, 4 waves; 3-buffer ring, counted vmcnt -----------
// LDS map (bytes): [0,24576) A[3][8192]  [24576,73728) B[3][16384]
// Epilogue reuses: floats [0,1024) wsd [1024,2048) delta [2048,2304) base
//                  [2304,2560) woa [2560,2816) wo2 [2816,3072) bl
__global__ __launch_bounds__(256, 2) void fused_main(
    const float* __restrict__ llm, const float* __restrict__ bl,
    const float* __restrict__ Wo, const float* __restrict__ bo,
    const float* __restrict__ wf, float* __restrict__ out) {

  __shared__ __align__(16) char smem[73728];
  __shared__ float csd_s[4];
  __shared__ float a_s[64][4];
  __shared__ float r2_s[64];
  __shared__ float p2_s[4][64];

  const int t = threadIdx.x;
  const int w = t >> 6, l = t & 63, g = l >> 4, c = l & 15;
  const int m0 = blockIdx.x * 64;
  const char* BsB = (const char*)(wf + 4096);

  // stage one K-tile (kk) into ring buffer buf: A 8 KB (2 rounds) + B 16 KB
  // (4 rounds); 6 gl_lds instructions per wave total.
  auto stage = [&](int buf, int kk) {
    char* abase = smem + buf * 8192 + w * 1024;
    #pragma unroll
    for (int r = 0; r < 2; ++r) {
      const int chunk = r * 256 + w * 64 + l;        // 16B-chunk index
      const int row = chunk >> 3;                    // 0..63
      const int cb = (chunk & 7) * 16;               // physical col-byte
      const int cl = cb ^ ((row & 7) << 4);          // inverse-swizzled source
      const char* gp = (const char*)(llm + (size_t)(m0 + row) * 768 + kk * 32) + cl;
      gl_lds16(gp, abase + r * 4096);
    }
    char* bbase = smem + 24576 + buf * 16384 + w * 1024;
    const char* gb = BsB + (size_t)kk * 16384;
    #pragma unroll
    for (int r = 0; r < 4; ++r) {
      const int chunk = r * 256 + w * 64 + l;
      gl_lds16(gb + (size_t)chunk * 16, bbase + r * 4096);
    }
  };

  stage(0, 0);
  stage(1, 1);

  f32x4 acc[16] = {};
  const int row_l = w * 16 + c;                 // this lane's A row in tile
  const int sro = row_l * 128;
  const int sxor = (row_l & 7) << 4;

  #pragma unroll 3
  for (int kk = 0; kk < 24; ++kk) {
    const int cur = kk % 3;
    if (kk < 22) stage((kk + 2) % 3, kk + 2);   // keep ring full
    if (kk < 22)      VMCNT(12);                // wait tile kk only (6 ops)
    else if (kk < 23) VMCNT(6);
    else              VMCNT(0);
    __builtin_amdgcn_s_barrier();               // tile kk visible to all waves
    __builtin_amdgcn_sched_barrier(0);

    const char* ab = smem + cur * 8192 + sro;
    const float4 fa = *(const float4*)(ab + ((g * 32) ^ sxor));
    const float4 fb = *(const float4*)(ab + ((g * 32 + 16) ^ sxor));
    uint4 pk;
    pk.x = f2bf(fa.x) | (f2bf(fa.y) << 16);
    pk.y = f2bf(fa.z) | (f2bf(fa.w) << 16);
    pk.z = f2bf(fb.x) | (f2bf(fb.y) << 16);
    pk.w = f2bf(fb.z) | (f2bf(fb.w) << 16);
    const bf16x8 afr = __builtin_bit_cast(bf16x8, pk);

    const char* bb = smem + 24576 + cur * 16384 + l * 16;
    #pragma unroll
    for (int nt = 0; nt < 16; ++nt) {
      const bf16x8 bfr = *(const bf16x8*)(bb + nt * 1024);
      acc[nt] = __builtin_amdgcn_mfma_f32_16x16x32_bf16(afr, bfr, acc[nt], 0, 0, 0);
    }
    __builtin_amdgcn_sched_barrier(0);
    __builtin_amdgcn_s_barrier();               // readers done before overwrite
  }

  // ---- epilogue tables into (now free) staging LDS ----
  float* wsd_s  = (float*)smem;          // [1024]
  float* delta_s = (float*)smem + 1024;  // [1024]
  float* base_s = (float*)smem + 2048;   // [256]
  float* woa_s  = (float*)smem + 2304;   // [256]
  float* wo2_s  = (float*)smem + 2560;   // [256]
  float* bl_s   = (float*)smem + 2816;   // [256]
  for (int i = t; i < 1024; i += 256) { wsd_s[i] = wf[1536 + i]; delta_s[i] = wf[2816 + i]; }
  base_s[t] = wf[2560 + t];
  woa_s[t] = Wo[t];
  wo2_s[t] = Wo[256 + t];
  bl_s[t] = bl[t];
  if (t < 4) csd_s[t] = wf[3840 + t];
  __syncthreads();

  // Pass 1: per-row sdiff[h] and relu(l).Wo2 partials, reduce over 16 lanes.
  // C layout: row = g*4 + j (within wave's 16 rows), col = nt*16 + c.
  float psd[4][4] = {};
  float pr2[4] = {};
  #pragma unroll
  for (int nt = 0; nt < 16; ++nt) {
    const int col = nt * 16 + c;
    const float w0 = wsd_s[col], w1 = wsd_s[256 + col], w2 = wsd_s[512 + col], w3 = wsd_s[768 + col];
    const float wo = wo2_s[col], bb2 = bl_s[col];
    #pragma unroll
    for (int j = 0; j < 4; ++j) {
      const float x = acc[nt][j] + bb2;
      psd[j][0] = fmaf(x, w0, psd[j][0]);
      psd[j][1] = fmaf(x, w1, psd[j][1]);
      psd[j][2] = fmaf(x, w2, psd[j][2]);
      psd[j][3] = fmaf(x, w3, psd[j][3]);
      pr2[j] = fmaf(fmaxf(x, 0.f), wo, pr2[j]);
    }
  }
  #pragma unroll
  for (int off = 8; off; off >>= 1) {
    #pragma unroll
    for (int j = 0; j < 4; ++j) {
      #pragma unroll
      for (int h = 0; h < 4; ++h) psd[j][h] += __shfl_xor(psd[j][h], off);
      pr2[j] += __shfl_xor(pr2[j], off);
    }
  }
  if (c == 0) {
    #pragma unroll
    for (int j = 0; j < 4; ++j) {
      const int r = w * 16 + g * 4 + j;
      #pragma unroll
      for (int h = 0; h < 4; ++h)
        a_s[r][h] = 1.f / (1.f + __expf(-(psd[j][h] + csd_s[h])));
      r2_s[r] = pr2[j];
    }
  }
  __syncthreads();

  // Pass 2: attended reconstruction + relu-dot, 4 col-quarters x 64 rows.
  {
    const int r = t & 63, q = t >> 6;
    const float a0 = a_s[r][0], a1 = a_s[r][1], a2 = a_s[r][2], a3 = a_s[r][3];
    float p = 0.f;
    const int j0 = q * 64;
    #pragma unroll 4
    for (int j = j0; j < j0 + 64; ++j) {
      float att = base_s[j];
      att = fmaf(a0, delta_s[j], att);
      att = fmaf(a1, delta_s[256 + j], att);
      att = fmaf(a2, delta_s[512 + j], att);
      att = fmaf(a3, delta_s[768 + j], att);
      p = fmaf(fmaxf(att, 0.f), woa_s[j], p);
    }
    p2_s[q][r] = p;
  }
  __syncthreads();
  if (t < 64)
    out[m0 + t] = p2_s[0][t] + p2_s[1][t] + p2_s[2][t] + p2_s[3][t] + r2_s[t] + bo[0];
}

// ---------------------------------------------------------------------------
extern "C" void kernel_launch(void* const* d_in, const int* in_sizes, int n_in,
                              void* d_out, int out_size, void* d_ws, size_t ws_size,
                              hipStream_t stream) {
  const float* user  = (const float*)d_in[0];
  const float* query = (const float*)d_in[1];
  const float* llm   = (const float*)d_in[2];
  const float* Wu    = (const float*)d_in[3];
  const float* bu    = (const float*)d_in[4];
  const float* Wq    = (const float*)d_in[5];
  const float* bq    = (const float*)d_in[6];
  const float* Wl    = (const float*)d_in[7];
  const float* bl    = (const float*)d_in[8];
  const float* ipw   = (const float*)d_in[9];
  const float* ipb   = (const float*)d_in[10];
  const float* opw   = (const float*)d_in[11];
  const float* opb   = (const float*)d_in[12];
  const float* Wo    = (const float*)d_in[13];
  const float* bo    = (const float*)d_in[14];
  float* out = (float*)d_out;
  float* wf = (float*)d_ws;
  unsigned int* Bs4 = (unsigned int*)(wf + 4096);

  prep_all<<<97, 256, 0, stream>>>(user, query, Wu, bu, Wq, bq, Wl,
                                   ipw, ipb, opw, opb, wf, Bs4);
  fused_main<<<131072 / 64, 256, 0, stream>>>(llm, bl, Wo, bo, wf, out);
}

// Round 4
// 167.649 us; speedup vs baseline: 1.6599x; 1.6599x over previous
//
#include <hip/hip_runtime.h>

// ---------------------------------------------------------------------------
// PreferencePredictor: logits[m] over M=131072 candidates.
// Heavy op: l = llm @ Wl^T  (M=131072, K=768, N=256)  -> HBM-bound (403 MB).
// Attention over 2 ctx rows collapses to 4 sigmoid gates + rank-4 update with
// precomputed wsd/csd/base/delta (prep kernels).
// Main loop: 2-buffer global_load_lds double-buffer with COUNTED vmcnt(6)
// (T4): next tile's 6 DMA ops stay in flight across the barrier; vmcnt never
// drains to 0 until the last step. A staged fp32 with XOR swizzle (row&7)<<4
// (linear LDS dest + inverse-swizzled global src); B staged in MFMA fragment
// order (prep_w pre-swizzled, linear both sides). 51.5 KB LDS -> 3 blocks/CU.
// ws float layout:
//   [0,256) u   [256,512) qv   [512,768) k0  [768,1024) k1
//   [1024,1280) v0  [1280,1536) v1
//   [1536,2560) wsd[4][256]   [2560,2816) base[256]
//   [2816,3840) delta[4][256] [3840,3844) csd[4]
//   float idx 4096: Bs bf16 fragment order Bs[kk(24)][nt(16)][lane(64)][i(8)]
// ---------------------------------------------------------------------------

typedef float f32x4 __attribute__((ext_vector_type(4)));
typedef __bf16 bf16x8 __attribute__((ext_vector_type(8)));

#define VMCNT(n) asm volatile("s_waitcnt vmcnt(" #n ")" ::: "memory")

__device__ __forceinline__ unsigned f2bf(float f) {
  unsigned u = __builtin_bit_cast(unsigned, f);
  u += 0x7fffu + ((u >> 16) & 1u);   // round-to-nearest-even
  return u >> 16;
}

__device__ __forceinline__ void gl_lds16(const void* g, void* l) {
  __builtin_amdgcn_global_load_lds(
      (const __attribute__((address_space(1))) void*)g,
      (__attribute__((address_space(3))) void*)l, 16, 0, 0);
}

// ---- prep_a: u = user@Wu^T+bu, qv = query@Wq^T+bq  (64 blocks x 256) ------
__global__ void prep_a(const float* __restrict__ user, const float* __restrict__ query,
                       const float* __restrict__ Wu, const float* __restrict__ bu,
                       const float* __restrict__ Wq, const float* __restrict__ bq,
                       float* __restrict__ wf) {
  const int og = threadIdx.x >> 5, ln = threadIdx.x & 31;
  const int o = blockIdx.x * 8 + og;        // 0..511
  const int isq = o >> 8, j = o & 255;
  const float* Wrow = (isq ? Wq : Wu) + (size_t)j * 768;
  const float* vec = isq ? query : user;
  float p = 0.f;
  #pragma unroll
  for (int i = 0; i < 24; ++i) { int d = ln * 24 + i; p = fmaf(Wrow[d], vec[d], p); }
  #pragma unroll
  for (int off = 16; off; off >>= 1) p += __shfl_xor(p, off);
  if (ln == 0) wf[o] = p + (isq ? bq[j] : bu[j]);
}

// ---- prep_b: k0,k1,v0,v1 from ctx={u,qv}  (128 blocks x 256) --------------
__global__ void prep_b(const float* __restrict__ ipw, const float* __restrict__ ipb,
                       float* __restrict__ wf) {
  const int og = threadIdx.x >> 5, ln = threadIdx.x & 31;
  const int o = blockIdx.x * 8 + og;        // 0..1023
  const int kv = o >> 9, cc = (o >> 8) & 1, j = o & 255;
  const int row = 256 + kv * 256 + j;
  const float* Wrow = ipw + (size_t)row * 256;
  const float* ctx = wf + cc * 256;
  float p = 0.f;
  #pragma unroll
  for (int i = 0; i < 8; ++i) { int d = ln * 8 + i; p = fmaf(Wrow[d], ctx[d], p); }
  #pragma unroll
  for (int off = 16; off; off >>= 1) p += __shfl_xor(p, off);
  if (ln == 0) wf[512 + o] = p + ipb[row];
}

// ---- prep_c: wsd, csd (blocks 0-3), base, delta (block 4)  (5 x 256) ------
__global__ void prep_c(const float* __restrict__ ipw, const float* __restrict__ ipb,
                       const float* __restrict__ opw, const float* __restrict__ opb,
                       float* __restrict__ wf) {
  const int t = threadIdx.x, b = blockIdx.x;
  if (b < 4) {
    const int h = b;
    float acc = 0.f;
    for (int d = 0; d < 64; ++d) {
      float kd = wf[512 + h * 64 + d] - wf[768 + h * 64 + d];
      acc = fmaf(ipw[(size_t)(h * 64 + d) * 256 + t], kd, acc);
    }
    wf[1536 + h * 256 + t] = 0.125f * acc;
    if (t == 0) {
      float cs = 0.f;
      for (int d = 0; d < 64; ++d)
        cs = fmaf(ipb[h * 64 + d], wf[512 + h * 64 + d] - wf[768 + h * 64 + d], cs);
      wf[3840 + h] = 0.125f * cs;
    }
  } else {
    const float* oprow = opw + (size_t)t * 256;
    float bse = 0.f;
    for (int i = 0; i < 256; ++i) bse = fmaf(oprow[i], wf[1280 + i], bse);
    wf[2560 + t] = bse + opb[t];
    #pragma unroll
    for (int h = 0; h < 4; ++h) {
      float dl = 0.f;
      for (int d = 0; d < 64; ++d)
        dl = fmaf(oprow[h * 64 + d], wf[1024 + h * 64 + d] - wf[1280 + h * 64 + d], dl);
      wf[2816 + h * 256 + t] = dl;
    }
  }
}

// ---- prep_w: Wl fp32 -> bf16, pre-swizzled B-fragment layout (96 x 256) ---
__global__ void prep_w(const float* __restrict__ Wl, unsigned int* __restrict__ Bs4) {
  const int tid = blockIdx.x * 256 + threadIdx.x;   // (kk*16+nt)*64+lane
  const int lane = tid & 63;
  const int ntk = tid >> 6;
  const int kk = ntk >> 4, nt = ntk & 15;
  const int k = kk * 32 + (lane >> 4) * 8;
  const int j = nt * 16 + (lane & 15);
  const float* src = Wl + (size_t)j * 768 + k;
  uint4 pk;
  pk.x = f2bf(src[0]) | (f2bf(src[1]) << 16);
  pk.y = f2bf(src[2]) | (f2bf(src[3]) << 16);
  pk.z = f2bf(src[4]) | (f2bf(src[5]) << 16);
  pk.w = f2bf(src[6]) | (f2bf(src[7]) << 16);
  ((uint4*)Bs4)[tid] = pk;
}

// ---- main: 64 rows/block, 4 waves; 2-buffer + counted vmcnt ---------------
// LDS map (bytes): [0,16384) A[2][8192]  [16384,49152) B[2][16384]
// Epilogue reuses: floats [0,1024) wsd [1024,2048) delta [2048,2304) base
//                  [2304,2560) woa [2560,2816) wo2 [2816,3072) bl
__global__ __launch_bounds__(256, 3) void fused_main(
    const float* __restrict__ llm, const float* __restrict__ bl,
    const float* __restrict__ Wo, const float* __restrict__ bo,
    const float* __restrict__ wf, float* __restrict__ out) {

  __shared__ __align__(16) char smem[49152];
  __shared__ float csd_s[4];
  __shared__ float a_s[64][4];
  __shared__ float r2_s[64];
  __shared__ float p2_s[4][64];

  const int t = threadIdx.x;
  const int w = t >> 6, l = t & 63, g = l >> 4, c = l & 15;
  const int m0 = blockIdx.x * 64;
  const char* BsB = (const char*)(wf + 4096);

  // stage one K-tile into buf: A 8 KB (2 rounds) + B 16 KB (4 rounds);
  // exactly 6 gl_lds instructions per wave.
  auto stage = [&](int buf, int kk) {
    char* abase = smem + buf * 8192 + w * 1024;
    #pragma unroll
    for (int r = 0; r < 2; ++r) {
      const int chunk = r * 256 + w * 64 + l;        // 16B-chunk index
      const int row = chunk >> 3;                    // 0..63
      const int cb = (chunk & 7) * 16;               // physical col-byte
      const int cl = cb ^ ((row & 7) << 4);          // inverse-swizzled source
      const char* gp = (const char*)(llm + (size_t)(m0 + row) * 768 + kk * 32) + cl;
      gl_lds16(gp, abase + r * 4096);
    }
    char* bbase = smem + 16384 + buf * 16384 + w * 1024;
    const char* gb = BsB + (size_t)kk * 16384;
    #pragma unroll
    for (int r = 0; r < 4; ++r) {
      const int chunk = r * 256 + w * 64 + l;
      gl_lds16(gb + (size_t)chunk * 16, bbase + r * 4096);
    }
  };

  stage(0, 0);

  f32x4 acc[16] = {};
  const int row_l = w * 16 + c;                 // this lane's A row in tile
  const int sro = row_l * 128;
  const int sxor = (row_l & 7) << 4;

  for (int kk = 0; kk < 24; ++kk) {
    const int cur = kk & 1;
    if (kk < 23) { stage(cur ^ 1, kk + 1); VMCNT(6); }  // tile kk done; kk+1 in flight
    else         { VMCNT(0); }
    __builtin_amdgcn_s_barrier();               // tile kk visible to all waves

    const char* ab = smem + cur * 8192 + sro;
    const float4 fa = *(const float4*)(ab + ((g * 32) ^ sxor));
    const float4 fb = *(const float4*)(ab + ((g * 32 + 16) ^ sxor));
    uint4 pk;
    pk.x = f2bf(fa.x) | (f2bf(fa.y) << 16);
    pk.y = f2bf(fa.z) | (f2bf(fa.w) << 16);
    pk.z = f2bf(fb.x) | (f2bf(fb.y) << 16);
    pk.w = f2bf(fb.z) | (f2bf(fb.w) << 16);
    const bf16x8 afr = __builtin_bit_cast(bf16x8, pk);

    const char* bb = smem + 16384 + cur * 16384 + l * 16;
    #pragma unroll
    for (int nt = 0; nt < 16; ++nt) {
      const bf16x8 bfr = *(const bf16x8*)(bb + nt * 1024);
      acc[nt] = __builtin_amdgcn_mfma_f32_16x16x32_bf16(afr, bfr, acc[nt], 0, 0, 0);
    }
    __builtin_amdgcn_s_barrier();               // readers done before overwrite
  }

  // ---- epilogue tables into (now free) staging LDS ----
  float* wsd_s  = (float*)smem;          // [1024]
  float* delta_s = (float*)smem + 1024;  // [1024]
  float* base_s = (float*)smem + 2048;   // [256]
  float* woa_s  = (float*)smem + 2304;   // [256]
  float* wo2_s  = (float*)smem + 2560;   // [256]
  float* bl_s   = (float*)smem + 2816;   // [256]
  for (int i = t; i < 1024; i += 256) { wsd_s[i] = wf[1536 + i]; delta_s[i] = wf[2816 + i]; }
  base_s[t] = wf[2560 + t];
  woa_s[t] = Wo[t];
  wo2_s[t] = Wo[256 + t];
  bl_s[t] = bl[t];
  if (t < 4) csd_s[t] = wf[3840 + t];
  __syncthreads();

  // Pass 1: per-row sdiff[h] and relu(l).Wo2 partials, reduce over 16 lanes.
  // C layout: row = g*4 + j (within wave's 16 rows), col = nt*16 + c.
  float psd[4][4] = {};
  float pr2[4] = {};
  #pragma unroll
  for (int nt = 0; nt < 16; ++nt) {
    const int col = nt * 16 + c;
    const float w0 = wsd_s[col], w1 = wsd_s[256 + col], w2 = wsd_s[512 + col], w3 = wsd_s[768 + col];
    const float wo = wo2_s[col], bb2 = bl_s[col];
    #pragma unroll
    for (int j = 0; j < 4; ++j) {
      const float x = acc[nt][j] + bb2;
      psd[j][0] = fmaf(x, w0, psd[j][0]);
      psd[j][1] = fmaf(x, w1, psd[j][1]);
      psd[j][2] = fmaf(x, w2, psd[j][2]);
      psd[j][3] = fmaf(x, w3, psd[j][3]);
      pr2[j] = fmaf(fmaxf(x, 0.f), wo, pr2[j]);
    }
  }
  #pragma unroll
  for (int off = 8; off; off >>= 1) {
    #pragma unroll
    for (int j = 0; j < 4; ++j) {
      #pragma unroll
      for (int h = 0; h < 4; ++h) psd[j][h] += __shfl_xor(psd[j][h], off);
      pr2[j] += __shfl_xor(pr2[j], off);
    }
  }
  if (c == 0) {
    #pragma unroll
    for (int j = 0; j < 4; ++j) {
      const int r = w * 16 + g * 4 + j;
      #pragma unroll
      for (int h = 0; h < 4; ++h)
        a_s[r][h] = 1.f / (1.f + __expf(-(psd[j][h] + csd_s[h])));
      r2_s[r] = pr2[j];
    }
  }
  __syncthreads();

  // Pass 2: attended reconstruction + relu-dot, 4 col-quarters x 64 rows.
  {
    const int r = t & 63, q = t >> 6;
    const float a0 = a_s[r][0], a1 = a_s[r][1], a2 = a_s[r][2], a3 = a_s[r][3];
    float p = 0.f;
    const int j0 = q * 64;
    #pragma unroll 4
    for (int j = j0; j < j0 + 64; ++j) {
      float att = base_s[j];
      att = fmaf(a0, delta_s[j], att);
      att = fmaf(a1, delta_s[256 + j], att);
      att = fmaf(a2, delta_s[512 + j], att);
      att = fmaf(a3, delta_s[768 + j], att);
      p = fmaf(fmaxf(att, 0.f), woa_s[j], p);
    }
    p2_s[q][r] = p;
  }
  __syncthreads();
  if (t < 64)
    out[m0 + t] = p2_s[0][t] + p2_s[1][t] + p2_s[2][t] + p2_s[3][t] + r2_s[t] + bo[0];
}

// ---------------------------------------------------------------------------
extern "C" void kernel_launch(void* const* d_in, const int* in_sizes, int n_in,
                              void* d_out, int out_size, void* d_ws, size_t ws_size,
                              hipStream_t stream) {
  const float* user  = (const float*)d_in[0];
  const float* query = (const float*)d_in[1];
  const float* llm   = (const float*)d_in[2];
  const float* Wu    = (const float*)d_in[3];
  const float* bu    = (const float*)d_in[4];
  const float* Wq    = (const float*)d_in[5];
  const float* bq    = (const float*)d_in[6];
  const float* Wl    = (const float*)d_in[7];
  const float* bl    = (const float*)d_in[8];
  const float* ipw   = (const float*)d_in[9];
  const float* ipb   = (const float*)d_in[10];
  const float* opw   = (const float*)d_in[11];
  const float* opb   = (const float*)d_in[12];
  const float* Wo    = (const float*)d_in[13];
  const float* bo    = (const float*)d_in[14];
  float* out = (float*)d_out;
  float* wf = (float*)d_ws;
  unsigned int* Bs4 = (unsigned int*)(wf + 4096);

  prep_a<<<64, 256, 0, stream>>>(user, query, Wu, bu, Wq, bq, wf);
  prep_w<<<96, 256, 0, stream>>>(Wl, Bs4);
  prep_b<<<128, 256, 0, stream>>>(ipw, ipb, wf);
  prep_c<<<5, 256, 0, stream>>>(ipw, ipb, opw, opb, wf);
  fused_main<<<131072 / 64, 256, 0, stream>>>(llm, bl, Wo, bo, wf, out);
}